// Round 1
// baseline (660.553 us; speedup 1.0000x reference)
//
#include <hip/hip_runtime.h>

#define C_FEAT 128
#define C_EDGE 32
#define K1 288

typedef __attribute__((ext_vector_type(8))) short bf16x8;
typedef __attribute__((ext_vector_type(4))) float f32x4;

__device__ __forceinline__ short f2bf(float x) {
    union { float f; unsigned u; } v; v.f = x;
    unsigned r = v.u + 0x7fffu + ((v.u >> 16) & 1u);   // RTN-even
    return (short)(r >> 16);
}

__device__ __forceinline__ bf16x8 cvt8(float4 a, float4 b) {
    bf16x8 r;
    r[0] = f2bf(a.x); r[1] = f2bf(a.y); r[2] = f2bf(a.z); r[3] = f2bf(a.w);
    r[4] = f2bf(b.x); r[5] = f2bf(b.y); r[6] = f2bf(b.z); r[7] = f2bf(b.w);
    return r;
}

// Pack W[k][f] (f32) -> wp[(k/8)*128*8 + f*8 + (k%8)] (bf16) so a B-fragment
// (8 consecutive k for fixed f) is one coalesced 16B load per lane.
__global__ void prep_w(const float* __restrict__ W1, const float* __restrict__ W2,
                       short* __restrict__ w1p, short* __restrict__ w2p) {
    int idx = blockIdx.x * 256 + threadIdx.x;
    if (idx < K1 * C_FEAT) {
        int k = idx >> 7, f = idx & 127;
        w1p[(((k >> 3) * C_FEAT + f) << 3) + (k & 7)] = f2bf(W1[idx]);
    }
    if (idx < C_FEAT * C_FEAT) {
        int k = idx >> 7, f = idx & 127;
        w2p[(((k >> 3) * C_FEAT + f) << 3) + (k & 7)] = f2bf(W2[idx]);
    }
}

__global__ void copy_f4(const float4* __restrict__ s, float4* __restrict__ d, int n4) {
    int i = blockIdx.x * 256 + threadIdx.x;
    if (i < n4) d[i] = s[i];
}

__global__ void bias_copy(const float4* __restrict__ s, const float* __restrict__ bias,
                          float4* __restrict__ d, int n4) {
    int i = blockIdx.x * 256 + threadIdx.x;
    if (i < n4) {
        float4 v = s[i];
        float4 b = ((const float4*)bias)[i & 31];   // 128 feats = 32 float4 per row
        d[i] = make_float4(v.x + b.x, v.y + b.y, v.z + b.z, v.w + b.w);
    }
}

// One block = 64 edges x 128 features. 4 waves; wave w owns edges [w*16, w*16+16).
// Layer1: K=288 (h[ei] | h[ej] | edge_attr), layer2: K=128. Scatter-add by ej.
__global__ __launch_bounds__(256) void edge_mlp(
    const float* __restrict__ h, float* __restrict__ hdst,
    const int* __restrict__ ei, const int* __restrict__ ej,
    const float* __restrict__ ea,
    const short* __restrict__ w1p, const float* __restrict__ be1,
    const short* __restrict__ w2p, const float* __restrict__ be2, int E)
{
    __shared__ short Hs[64][136];   // 136 = 128 + 8 pad, rows stay 16B-aligned
    const int tid  = threadIdx.x;
    const int wave = tid >> 6, lane = tid & 63;
    const int l15  = lane & 15, q = lane >> 4;
    const int ewave = blockIdx.x * 64 + wave * 16;
    const int eg  = ewave + l15;               // this lane's gather edge (A row m)
    const int egc = eg < E ? eg : E - 1;
    const int ni = ei[egc];
    const int nj = ej[egc];

    f32x4 acc[8];
#pragma unroll
    for (int nt = 0; nt < 8; ++nt) acc[nt] = (f32x4){0.f, 0.f, 0.f, 0.f};

    // ---- layer 1: 9 K-chunks of 32 (4x h_i, 4x h_j, 1x edge_attr) ----
#pragma unroll
    for (int c = 0; c < 9; ++c) {
        const float* asrc;
        if (c < 4)      asrc = h + (size_t)ni * C_FEAT + c * 32 + q * 8;
        else if (c < 8) asrc = h + (size_t)nj * C_FEAT + (c - 4) * 32 + q * 8;
        else            asrc = ea + (size_t)egc * C_EDGE + q * 8;
        float4 a0 = ((const float4*)asrc)[0];
        float4 a1 = ((const float4*)asrc)[1];
        bf16x8 af = cvt8(a0, a1);   // A[m=l15][k=q*8+j]
        const short* bb = w1p + ((c * 4 + q) * C_FEAT) * 8;
#pragma unroll
        for (int nt = 0; nt < 8; ++nt) {
            bf16x8 bf = *(const bf16x8*)(bb + (nt * 16 + l15) * 8);  // B[k][n=l15]
            acc[nt] = __builtin_amdgcn_mfma_f32_16x16x32_bf16(af, bf, acc[nt], 0, 0, 0);
        }
    }

    // ---- ReLU + be1, C-layout (row=q*4+r, col=l15) -> LDS -> A-layout ----
#pragma unroll
    for (int nt = 0; nt < 8; ++nt) {
        int f = nt * 16 + l15;
        float b = be1[f];
#pragma unroll
        for (int r = 0; r < 4; ++r) {
            float v = acc[nt][r] + b;
            Hs[wave * 16 + q * 4 + r][f] = f2bf(v > 0.f ? v : 0.f);
        }
    }
    __syncthreads();

    f32x4 acc2[8];
#pragma unroll
    for (int nt = 0; nt < 8; ++nt) acc2[nt] = (f32x4){0.f, 0.f, 0.f, 0.f};

    // ---- layer 2: K=128, 4 chunks ----
#pragma unroll
    for (int c = 0; c < 4; ++c) {
        bf16x8 af = *(const bf16x8*)(&Hs[wave * 16 + l15][c * 32 + q * 8]);
        const short* bb = w2p + ((c * 4 + q) * C_FEAT) * 8;
#pragma unroll
        for (int nt = 0; nt < 8; ++nt) {
            bf16x8 bf = *(const bf16x8*)(bb + (nt * 16 + l15) * 8);
            acc2[nt] = __builtin_amdgcn_mfma_f32_16x16x32_bf16(af, bf, acc2[nt], 0, 0, 0);
        }
    }

    // ---- + be2, scatter-add rows to hdst[ej[e]] ----
    float b2v[8];
#pragma unroll
    for (int nt = 0; nt < 8; ++nt) b2v[nt] = be2[nt * 16 + l15];

#pragma unroll
    for (int r = 0; r < 4; ++r) {
        int e = ewave + q * 4 + r;      // C row = edge within tile
        if (e < E) {
            int tn = ej[e];
            float* dst = hdst + (size_t)tn * C_FEAT;
#pragma unroll
            for (int nt = 0; nt < 8; ++nt) {
                unsafeAtomicAdd(dst + nt * 16 + l15, acc2[nt][r] + b2v[nt]);
            }
        }
    }
}

extern "C" void kernel_launch(void* const* d_in, const int* in_sizes, int n_in,
                              void* d_out, int out_size, void* d_ws, size_t ws_size,
                              hipStream_t stream) {
    const float* x    = (const float*)d_in[0];
    const int*   eidx = (const int*)  d_in[1];
    const float* ea   = (const float*)d_in[2];
    const float* We1  = (const float*)d_in[3];
    const float* be1  = (const float*)d_in[4];
    const float* We2  = (const float*)d_in[5];
    const float* be2  = (const float*)d_in[6];
    const float* bias = (const float*)d_in[7];
    float* out = (float*)d_out;

    const int E = in_sizes[1] / 2;
    const int N = in_sizes[0] / C_FEAT;
    const int* ei = eidx;
    const int* ej = eidx + E;

    // workspace: [ h1 buffer (N*128 f32) | W1 packed bf16 | W2 packed bf16 ]
    float* bufA = (float*)d_ws;
    short* w1p  = (short*)((char*)d_ws + (size_t)N * C_FEAT * sizeof(float));
    short* w2p  = w1p + K1 * C_FEAT;

    const int n4 = N * C_FEAT / 4;
    const int cb = (n4 + 255) / 256;
    const int eb = (E + 63) / 64;

    prep_w<<<144, 256, 0, stream>>>(We1, We2, w1p, w2p);
    // step 1: bufA = x + segsum(m1)
    copy_f4<<<cb, 256, 0, stream>>>((const float4*)x, (float4*)bufA, n4);
    edge_mlp<<<eb, 256, 0, stream>>>(x, bufA, ei, ej, ea, w1p, be1, w2p, be2, E);
    // step 2: out = bufA + bias + segsum(m2)
    bias_copy<<<cb, 256, 0, stream>>>((const float4*)bufA, bias, (float4*)out, n4);
    edge_mlp<<<eb, 256, 0, stream>>>(bufA, out, ei, ej, ea, w1p, be1, w2p, be2, E);
}